// Round 1
// baseline (4425.361 us; speedup 1.0000x reference)
//
#include <hip/hip_runtime.h>

// LSTM encoder-decoder, MI355X. B=1024, S=256, IN=8, H=512, F=96, OUT=1.
// 352 sequential steps; each step: [1024,512]@[512,2048] fp16 MFMA GEMM + fused gates.
// Decoder feedback folded into weights: W' = Whh + out_w (x) dec_Wih (exact algebra).

#define Hh 512
#define FOURH 2048
#define BATCH 1024
#define SEQ 256
#define FCAST 96

typedef _Float16 f16;
typedef _Float16 f16x8 __attribute__((ext_vector_type(8)));
typedef float f32x4 __attribute__((ext_vector_type(4)));

__device__ __forceinline__ float sigf(float v) { return 1.0f / (1.0f + __expf(-v)); }
// safe tanh: exp(2x)=inf -> 1, exp(2x)=0 -> -1 (no inf/inf NaN)
__device__ __forceinline__ float tanhf_(float v) { return 1.0f - 2.0f / (__expf(2.0f * v) + 1.0f); }

// ---------------- prep: permute + fp16-convert weights ----------------
// Permutation: original row r = g*512 + j  (gate g in {i,f,g,o}, hidden j)
// -> col n = (j>>5)*128 + g*32 + (j&31). N-tile nt owns hidden [nt*32, nt*32+32) x 4 gates.
__global__ void prep_weights(const float* __restrict__ encWhh, const float* __restrict__ decWhh,
                             const float* __restrict__ decWih, const float* __restrict__ encWih,
                             const float* __restrict__ encBih, const float* __restrict__ encBhh,
                             const float* __restrict__ decBih, const float* __restrict__ decBhh,
                             const float* __restrict__ outW, const float* __restrict__ outB,
                             f16* __restrict__ encT, f16* __restrict__ decP, f16* __restrict__ decF,
                             float* __restrict__ wihPerm, float* __restrict__ biasEnc,
                             float* __restrict__ biasDecP, float* __restrict__ biasDecF) {
  int id = blockIdx.x * 256 + threadIdx.x;   // 512 blocks -> 131072 = 2048 * 64
  int n = id >> 6;
  int c8 = id & 63;
  int nt = n >> 7, g = (n >> 5) & 3, jl = n & 31;
  int r = g * 512 + nt * 32 + jl;
  float dwih = decWih[r];
#pragma unroll
  for (int e = 0; e < 8; ++e) {
    int k = c8 * 8 + e;
    encT[n * Hh + k] = (f16)encWhh[r * Hh + k];
    float dw = decWhh[r * Hh + k];
    decP[n * Hh + k] = (f16)dw;
    decF[n * Hh + k] = (f16)(dw + outW[k] * dwih);
  }
  if (c8 == 0) {
    biasEnc[n] = encBih[r] + encBhh[r];
    float bd = decBih[r] + decBhh[r];
    biasDecP[n] = bd;
    biasDecF[n] = bd + outB[0] * dwih;
#pragma unroll
    for (int k = 0; k < 8; ++k) wihPerm[n * 8 + k] = encWih[r * 8 + k];
  }
}

// ---------------- init: zero h/c, d_out = out_b ----------------
__global__ void init_state(f16* __restrict__ h0, f16* __restrict__ h1, float* __restrict__ c,
                           float* __restrict__ out, const float* __restrict__ outB) {
  int i = blockIdx.x * 256 + threadIdx.x;   // 2048 blocks covers 524288
  if (i < BATCH * Hh) { h0[i] = (f16)0.f; h1[i] = (f16)0.f; c[i] = 0.f; }
  if (i < BATCH * FCAST) out[i] = outB[0];
}

// ---------------- one LSTM step ----------------
// grid 256 = 16 M-tiles(64 rows) x 16 N-tiles(128 gate-cols = 32 units x 4 gates).
// K-chunks of 64 staged to LDS with register prefetch; 16x16x32 f16 MFMA.
template <bool IS_ENC>
__global__ __launch_bounds__(256, 1) void lstm_step(
    const f16* __restrict__ WT,      // [2048][512] permuted, n-major
    const float* __restrict__ bias,  // [2048] permuted
    const float* __restrict__ xAll,  // [1024][256][8] (enc only)
    int t,
    const f16* __restrict__ hIn,     // [1024][512]
    f16* __restrict__ hOut,          // [1024][512]
    float* __restrict__ cG,          // [1024][512] fp32
    const float* __restrict__ wihPerm,  // [2048][8] permuted (enc only)
    const float* __restrict__ outW,     // [512] (dec only)
    float* __restrict__ out, int pred_col) {
  constexpr int SAS = 72, SBS = 72, SGS = 132;  // padded strides (bank-conflict-free: 2-way max)
  __shared__ __align__(16) unsigned char smem_raw[64 * SGS * 4];  // 33792 B; stage needs 27648 B
  f16* sA = (f16*)smem_raw;            // [64][72]
  f16* sB = sA + 64 * SAS;             // [128][72]
  float* sG = (float*)smem_raw;        // [64][132] (aliases stage; used after K-loop)
  __shared__ float sX[64 * 8];
  __shared__ float sWih[128 * 8];
  __shared__ float sBias[128];
  __shared__ float sOw[32];

  const int T = threadIdx.x;
  const int mt = blockIdx.x >> 4, nt = blockIdx.x & 15;
  const int m0 = mt * 64, n0 = nt * 128, u0 = nt * 32;
  const int w = T >> 6, lane = T & 63;

  // small staging
  if (IS_ENC) {
    if (T < 128) {
      int row = T >> 1, half = T & 1;
      *(float4*)&sX[row * 8 + half * 4] =
          *(const float4*)&xAll[((m0 + row) * SEQ + t) * 8 + half * 4];
    }
    {
      int col = T >> 1, half = T & 1;
      *(float4*)&sWih[col * 8 + half * 4] = *(const float4*)&wihPerm[(n0 + col) * 8 + half * 4];
    }
  }
  if (T < 128) sBias[T] = bias[n0 + T];
  if (!IS_ENC && T < 32) sOw[T] = outW[u0 + T];

  f32x4 acc[2][4];
#pragma unroll
  for (int a = 0; a < 2; ++a)
#pragma unroll
    for (int b = 0; b < 4; ++b) acc[a][b] = (f32x4){0.f, 0.f, 0.f, 0.f};

  f16x8 aReg[2], bReg[4];
  auto loadChunk = [&](int chunk) {
    int k0 = chunk * 64;
#pragma unroll
    for (int j = 0; j < 2; ++j) {
      int id = T + 256 * j, row = id >> 3, c8 = id & 7;
      aReg[j] = *(const f16x8*)&hIn[(m0 + row) * Hh + k0 + c8 * 8];
    }
#pragma unroll
    for (int j = 0; j < 4; ++j) {
      int id = T + 256 * j, row = id >> 3, c8 = id & 7;
      bReg[j] = *(const f16x8*)&WT[(n0 + row) * Hh + k0 + c8 * 8];
    }
  };
  loadChunk(0);

  const int mw = (w & 1) * 32, nw = (w >> 1) * 64;
  for (int chunk = 0; chunk < 8; ++chunk) {
    __syncthreads();  // previous chunk's fragment reads complete
#pragma unroll
    for (int j = 0; j < 2; ++j) {
      int id = T + 256 * j, row = id >> 3, c8 = id & 7;
      *(f16x8*)&sA[row * SAS + c8 * 8] = aReg[j];
    }
#pragma unroll
    for (int j = 0; j < 4; ++j) {
      int id = T + 256 * j, row = id >> 3, c8 = id & 7;
      *(f16x8*)&sB[row * SBS + c8 * 8] = bReg[j];
    }
    __syncthreads();
    if (chunk < 7) loadChunk(chunk + 1);
#pragma unroll
    for (int ks = 0; ks < 2; ++ks) {
      int ko = ks * 32 + (lane >> 4) * 8;
      f16x8 af[2], bf[4];
#pragma unroll
      for (int at = 0; at < 2; ++at)
        af[at] = *(const f16x8*)&sA[(mw + at * 16 + (lane & 15)) * SAS + ko];
#pragma unroll
      for (int ct = 0; ct < 4; ++ct)
        bf[ct] = *(const f16x8*)&sB[(nw + ct * 16 + (lane & 15)) * SBS + ko];
#pragma unroll
      for (int at = 0; at < 2; ++at)
#pragma unroll
        for (int ct = 0; ct < 4; ++ct)
          acc[at][ct] = __builtin_amdgcn_mfma_f32_16x16x32_f16(af[at], bf[ct], acc[at][ct], 0, 0, 0);
    }
  }
  __syncthreads();  // all stage reads done before aliasing sG over sA/sB

  // accumulators -> sG (C/D layout: col=lane&15, row=(lane>>4)*4+reg)
#pragma unroll
  for (int at = 0; at < 2; ++at)
#pragma unroll
    for (int ct = 0; ct < 4; ++ct)
#pragma unroll
      for (int r = 0; r < 4; ++r) {
        int row = mw + at * 16 + (lane >> 4) * 4 + r;
        int col = nw + ct * 16 + (lane & 15);
        sG[row * SGS + col] = acc[at][ct][r];
      }
  __syncthreads();

  // pointwise: thread T handles unit jl = T&31, rows grp*8 .. grp*8+7
  {
    int jl = T & 31, grp = T >> 5;
    float ow = IS_ENC ? 0.f : sOw[jl];
    float pb[4];
#pragma unroll
    for (int g = 0; g < 4; ++g) pb[g] = sBias[g * 32 + jl];
    float wih[4][8];
    if (IS_ENC) {
#pragma unroll
      for (int g = 0; g < 4; ++g)
#pragma unroll
        for (int k = 0; k < 8; ++k) wih[g][k] = sWih[(g * 32 + jl) * 8 + k];
    }
#pragma unroll
    for (int rr = 0; rr < 8; ++rr) {
      int row = grp * 8 + rr;
      float p[4];
#pragma unroll
      for (int g = 0; g < 4; ++g) p[g] = sG[row * SGS + g * 32 + jl] + pb[g];
      if (IS_ENC) {
        float xv[8];
#pragma unroll
        for (int k = 0; k < 8; ++k) xv[k] = sX[row * 8 + k];
#pragma unroll
        for (int g = 0; g < 4; ++g)
#pragma unroll
          for (int k = 0; k < 8; ++k) p[g] += xv[k] * wih[g][k];
      }
      float ig = sigf(p[0]);
      float fg = sigf(p[1]);
      float gg = tanhf_(p[2]);
      float og = sigf(p[3]);
      int ci = (m0 + row) * Hh + u0 + jl;
      float cn = fg * cG[ci] + ig * gg;
      cG[ci] = cn;
      float hn = og * tanhf_(cn);
      hOut[ci] = (f16)hn;
      if (!IS_ENC) {
        float pp = hn * ow;  // partial of pred = h . out_w
        pp += __shfl_xor(pp, 1, 32);
        pp += __shfl_xor(pp, 2, 32);
        pp += __shfl_xor(pp, 4, 32);
        pp += __shfl_xor(pp, 8, 32);
        pp += __shfl_xor(pp, 16, 32);
        if (jl == 0) atomicAdd(&out[(m0 + row) * FCAST + pred_col], pp);
      }
    }
  }
}

extern "C" void kernel_launch(void* const* d_in, const int* in_sizes, int n_in, void* d_out,
                              int out_size, void* d_ws, size_t ws_size, hipStream_t stream) {
  const float* x = (const float*)d_in[0];
  const float* encWih = (const float*)d_in[1];
  const float* encWhh = (const float*)d_in[2];
  const float* encBih = (const float*)d_in[3];
  const float* encBhh = (const float*)d_in[4];
  const float* decWih = (const float*)d_in[5];
  const float* decWhh = (const float*)d_in[6];
  const float* decBih = (const float*)d_in[7];
  const float* decBhh = (const float*)d_in[8];
  const float* outW = (const float*)d_in[9];
  const float* outB = (const float*)d_in[10];
  float* out = (float*)d_out;

  char* ws = (char*)d_ws;
  f16* encT = (f16*)ws;                       // 2 MB
  f16* decP = encT + FOURH * Hh;              // 2 MB
  f16* decF = decP + FOURH * Hh;              // 2 MB
  f16* h0 = decF + FOURH * Hh;                // 1 MB
  f16* h1 = h0 + BATCH * Hh;                  // 1 MB
  float* cG = (float*)(h1 + BATCH * Hh);      // 2 MB
  float* wihPerm = cG + BATCH * Hh;           // 64 KB
  float* biasEnc = wihPerm + FOURH * 8;
  float* biasDecP = biasEnc + FOURH;
  float* biasDecF = biasDecP + FOURH;         // total ~10.3 MB

  prep_weights<<<512, 256, 0, stream>>>(encWhh, decWhh, decWih, encWih, encBih, encBhh, decBih,
                                        decBhh, outW, outB, encT, decP, decF, wihPerm, biasEnc,
                                        biasDecP, biasDecF);
  init_state<<<2048, 256, 0, stream>>>(h0, h1, cG, out, outB);

  f16* bufs[2] = {h0, h1};
  int s = 0;  // global step parity
  for (int t = 0; t < SEQ; ++t, ++s)
    lstm_step<true><<<256, 256, 0, stream>>>(encT, biasEnc, x, t, bufs[s & 1], bufs[(s + 1) & 1],
                                             cG, wihPerm, nullptr, out, -1);
  for (int t = 1; t <= FCAST; ++t, ++s) {
    const f16* Wt = (t == 1) ? decP : decF;
    const float* bs = (t == 1) ? biasDecP : biasDecF;
    lstm_step<false><<<256, 256, 0, stream>>>(Wt, bs, nullptr, 0, bufs[s & 1], bufs[(s + 1) & 1],
                                              cG, nullptr, outW, out, t - 1);
  }
}